// Round 18
// baseline (312.016 us; speedup 1.0000x reference)
//
#include <hip/hip_runtime.h>
#include <cstdint>
#include <cstddef>

#define NB 4
#define NN 2048
#define DD 384
#define NH 6

typedef float f4 __attribute__((ext_vector_type(4)));
typedef float f32x4 __attribute__((ext_vector_type(4)));
typedef short bf16x8 __attribute__((ext_vector_type(8)));
typedef unsigned u32x2 __attribute__((ext_vector_type(2)));

__device__ __forceinline__ float gelu_t(float x) {
  float x3 = x*x*x;
  return 0.5f*x*(1.0f + tanhf(0.7978845608028654f*(x + 0.044715f*x3)));
}

__device__ __forceinline__ unsigned short f2b(float f) {
  unsigned u = __builtin_bit_cast(unsigned, f);
  u += 0x7fffu + ((u >> 16) & 1u);
  return (unsigned short)(u >> 16);
}

__device__ __forceinline__ float b2f(unsigned short u) {
  return __builtin_bit_cast(float, ((unsigned)u) << 16);
}

__device__ __forceinline__ unsigned cvtpk(float a, float b) {
  unsigned r;
  asm("v_cvt_pk_bf16_f32 %0, %1, %2" : "=v"(r) : "v"(a), "v"(b));
  return r;
}

typedef __attribute__((address_space(1))) const void gvoid_t;
typedef __attribute__((address_space(3))) void lvoid_t;
__device__ __forceinline__ void gl16(const void* g, void* l) {
  __builtin_amdgcn_global_load_lds((gvoid_t*)g, (lvoid_t*)l, 16, 0, 0);
}

__device__ __forceinline__ unsigned long long shfl_xor_u64(unsigned long long v, int m) {
  unsigned lo = (unsigned)v, hi = (unsigned)(v >> 32);
  lo = (unsigned)__shfl_xor((int)lo, m);
  hi = (unsigned)__shfl_xor((int)hi, m);
  return ((unsigned long long)hi << 32) | lo;
}

// ---------- split (B,387,N) -> coords xyzw (B,N,4) incl. w=|p|^2, feats (B,N,384) ----------
__global__ __launch_bounds__(256) void split_k(const float* __restrict__ pts,
                                               float* __restrict__ coords,
                                               float* __restrict__ feats) {
  __shared__ float t[32][33];
  int b = blockIdx.z;
  int c0 = blockIdx.x*32, n0 = blockIdx.y*32;
  int tx = threadIdx.x, ty = threadIdx.y;
#pragma unroll
  for (int i = 0; i < 4; ++i) {
    int c = c0 + ty + i*8;
    if (c < 387) t[ty+i*8][tx] = pts[((size_t)b*387 + c)*NN + n0 + tx];
  }
  __syncthreads();
#pragma unroll
  for (int i = 0; i < 4; ++i) {
    int n = n0 + ty + i*8;
    int c = c0 + tx;
    if (c < 387) {
      float v = t[tx][ty+i*8];
      if (c < 3) coords[((size_t)b*NN + n)*4 + c] = v;
      else       feats[((size_t)b*NN + n)*DD + (c-3)] = v;
    }
    if (c0 == 0 && tx == 3) {
      float x = t[0][ty+i*8], y = t[1][ty+i*8], z = t[2][ty+i*8];
      coords[((size_t)b*NN + n)*4 + 3] = x*x + y*y + z*z;
    }
  }
}

// ---------- pack coords+feats -> (B,387,N) ----------
__global__ __launch_bounds__(256) void pack_k(const float* __restrict__ coords,
                                              const float* __restrict__ feats,
                                              float* __restrict__ out) {
  __shared__ float t[32][33];
  int b = blockIdx.z;
  int c0 = blockIdx.x*32, n0 = blockIdx.y*32;
  int tx = threadIdx.x, ty = threadIdx.y;
#pragma unroll
  for (int i = 0; i < 4; ++i) {
    int n = n0 + ty + i*8;
    int c = c0 + tx;
    if (c < 387) {
      float v = (c < 3) ? coords[((size_t)b*NN + n)*4 + c]
                        : feats[((size_t)b*NN + n)*DD + (c-3)];
      t[tx][ty+i*8] = v;
    }
  }
  __syncthreads();
#pragma unroll
  for (int i = 0; i < 4; ++i) {
    int c = c0 + ty + i*8;
    if (c < 387) out[((size_t)b*387 + c)*NN + n0 + tx] = t[ty+i*8][tx];
  }
}

// ---------- LayerNorm ----------
__device__ __forceinline__ void ln_body(const float* __restrict__ x,
                                        const float* __restrict__ g,
                                        const float* __restrict__ bb,
                                        unsigned short* __restrict__ o,
                                        int row) {
  int lane = threadIdx.x & 63;
  const float* xr = x + (size_t)row*DD;
  float v[6]; float s = 0.f;
#pragma unroll
  for (int i = 0; i < 6; ++i) { v[i] = xr[lane + i*64]; s += v[i]; }
#pragma unroll
  for (int off = 1; off < 64; off <<= 1) s += __shfl_xor(s, off);
  float mean = s * (1.f/384.f);
  float s2 = 0.f;
#pragma unroll
  for (int i = 0; i < 6; ++i) { float d = v[i] - mean; s2 += d*d; }
#pragma unroll
  for (int off = 1; off < 64; off <<= 1) s2 += __shfl_xor(s2, off);
  float rs = rsqrtf(s2*(1.f/384.f) + 1e-5f);
  unsigned short* orow = o + (size_t)row*DD;
#pragma unroll
  for (int i = 0; i < 6; ++i) {
    int c = lane + i*64;
    orow[c] = f2b((v[i]-mean)*rs*g[c] + bb[c]);
  }
}

__global__ __launch_bounds__(256) void ln_k(const float* __restrict__ x,
                                            const float* __restrict__ g,
                                            const float* __restrict__ bb,
                                            unsigned short* __restrict__ o) {
  ln_body(x, g, bb, o, blockIdx.x*4 + (threadIdx.x >> 6));
}

__global__ __launch_bounds__(256) void ln2_k(const float* __restrict__ x1,
                                             const float* __restrict__ g1,
                                             const float* __restrict__ b1,
                                             unsigned short* __restrict__ o1,
                                             const float* __restrict__ x2,
                                             const float* __restrict__ g2,
                                             const float* __restrict__ b2,
                                             unsigned short* __restrict__ o2) {
  int row = blockIdx.x*4 + (threadIdx.x >> 6);
  if (blockIdx.y == 0) ln_body(x1, g1, b1, o1, row);
  else                 ln_body(x2, g2, b2, o2, row);
}

// ---------- one-shot weight transpose+convert ----------
struct WSrcs { const float* p[13]; };

__global__ __launch_bounds__(256) void wtrans_k(WSrcs srcs, unsigned short* __restrict__ dst) {
  constexpr int KK[13]  = {384,384,384,384,768,384,384,384,384,384,768,384,768};
  constexpr int NW[13]  = {1152,384,384,384,384,384,384,384,384,384,384,768,384};
  constexpr int MD[13]  = {0,0,2,0,0,0,0,0,0,2,0,0,0};
  constexpr int OFF[13] = {0,442368,589824,737280,884736,1179648,1327104,1474560,
                           1622016,1769472,1916928,2211840,2506752};
  constexpr int PFX[14] = {0,432,576,720,864,1152,1296,1440,1584,1728,1872,2160,2448,2736};
  int bid = blockIdx.x;
  int e = 0;
  while (bid >= PFX[e+1]) ++e;
  int t = bid - PFX[e];
  int K = KK[e], N = NW[e];
  int ntiles = N >> 5;
  int kt = t / ntiles, nt = t - kt*ntiles;
  const float* src = srcs.p[e];
  __shared__ float T[32][33];
  int tx = threadIdx.x & 31, ty = threadIdx.x >> 5;
  int n = nt*32 + tx;
#pragma unroll
  for (int i = 0; i < 4; ++i) {
    int k = kt*32 + ty + i*8;
    float v = src[(size_t)k*N + n];
    if (MD[e] == 2) v = src[(size_t)(k+384)*N + n] - v;
    T[ty+i*8][tx] = v;
  }
  __syncthreads();
#pragma unroll
  for (int i = 0; i < 4; ++i) {
    int nn = nt*32 + ty + i*8;
    int kk = kt*32 + tx;
    dst[(size_t)OFF[e] + (size_t)nn*K + kk] = f2b(T[tx][ty+i*8]);
  }
}

// ---------- MFMA bf16 GEMM body (dbuf gl16 staging) ----------
template<int ACT, int ACC, int OB, int HALFM>
__device__ __forceinline__ void mgemm_body(const unsigned short* __restrict__ A, int lda,
                                           const unsigned short* __restrict__ Wt,
                                           const float* __restrict__ bias,
                                           void* __restrict__ Cv, int ldc, int cofs,
                                           int Kd, int bx, int by, char* lds) {
  constexpr int BM   = HALFM ? 64 : 128;
  constexpr int MT   = HALFM ? 2 : 4;
  constexpr int AG   = HALFM ? 2 : 4;
  constexpr int ABUF = BM*128;
  constexpr int BUFSZ = ABUF + 8192;
  int tid = threadIdx.x;
  int lane = tid & 63, w = tid >> 6, g = lane >> 4, c = lane & 15;
  int wr = w >> 1, wc = w & 1;
  int m0 = by*BM, n0 = bx*64;
  int lrow = lane >> 3;
  int cswz = ((lane & 7) ^ lrow)*8;

  f32x4 acc[MT][2];
#pragma unroll
  for (int mt = 0; mt < MT; ++mt)
#pragma unroll
    for (int nt = 0; nt < 2; ++nt) acc[mt][nt] = 0.f;

  int KT = Kd >> 6;
  {
    char* As = lds; char* Bs = lds + ABUF;
#pragma unroll
    for (int i = 0; i < AG; ++i) {
      int rb = i*32 + w*8;
      gl16(A + (size_t)(m0 + rb + lrow)*lda + cswz, As + rb*128);
    }
#pragma unroll
    for (int i = 0; i < 2; ++i) {
      int rb = i*32 + w*8;
      gl16(Wt + (size_t)(n0 + rb + lrow)*Kd + cswz, Bs + rb*128);
    }
  }
  __syncthreads();

  for (int kt = 0; kt < KT; ++kt) {
    char* Asc = lds + (kt & 1)*BUFSZ;
    char* Bsc = Asc + ABUF;
    if (kt + 1 < KT) {
      char* Asn = lds + ((kt + 1) & 1)*BUFSZ;
      char* Bsn = Asn + ABUF;
      int k0 = (kt + 1)*64;
#pragma unroll
      for (int i = 0; i < AG; ++i) {
        int rb = i*32 + w*8;
        gl16(A + (size_t)(m0 + rb + lrow)*lda + k0 + cswz, Asn + rb*128);
      }
#pragma unroll
      for (int i = 0; i < 2; ++i) {
        int rb = i*32 + w*8;
        gl16(Wt + (size_t)(n0 + rb + lrow)*Kd + k0 + cswz, Bsn + rb*128);
      }
    }
#pragma unroll
    for (int kb = 0; kb < 2; ++kb) {
      bf16x8 af[MT], bfr[2];
#pragma unroll
      for (int mt = 0; mt < MT; ++mt) {
        int row = wr*(BM/2) + mt*16 + c;
        int ch = (kb*4 + g) ^ (row & 7);
        af[mt] = *(const bf16x8*)(Asc + row*128 + ch*16);
      }
#pragma unroll
      for (int nt = 0; nt < 2; ++nt) {
        int row = wc*32 + nt*16 + c;
        int ch = (kb*4 + g) ^ (row & 7);
        bfr[nt] = *(const bf16x8*)(Bsc + row*128 + ch*16);
      }
#pragma unroll
      for (int mt = 0; mt < MT; ++mt)
#pragma unroll
        for (int nt = 0; nt < 2; ++nt)
          acc[mt][nt] = __builtin_amdgcn_mfma_f32_16x16x32_bf16(af[mt], bfr[nt], acc[mt][nt], 0, 0, 0);
    }
    __syncthreads();
  }

#pragma unroll
  for (int mt = 0; mt < MT; ++mt) {
#pragma unroll
    for (int nt = 0; nt < 2; ++nt) {
      int coln = n0 + wc*32 + nt*16 + c;
      float bval = bias ? bias[coln] : 0.f;
#pragma unroll
      for (int r = 0; r < 4; ++r) {
        int m = m0 + wr*(BM/2) + mt*16 + 4*g + r;
        float t = acc[mt][nt][r] + bval;
        if (ACT == 1) t = gelu_t(t);
        if (OB) {
          ((unsigned short*)Cv)[(size_t)m*ldc + cofs + coln] = f2b(t);
        } else {
          float* cp = (float*)Cv + (size_t)m*ldc + cofs + coln;
          if (ACC) t += *cp;
          *cp = t;
        }
      }
    }
  }
}

template<int ACT, int ACC, int OB, int HALFM>
__global__ __launch_bounds__(256) void mgemm_k(const unsigned short* __restrict__ A, int lda,
                                               const unsigned short* __restrict__ Wt,
                                               const float* __restrict__ bias,
                                               void* __restrict__ Cv, int ldc, int cofs,
                                               int Kd) {
  constexpr int BM = HALFM ? 64 : 128;
  __shared__ char lds[2*(BM*128 + 8192)];
  mgemm_body<ACT,ACC,OB,HALFM>(A, lda, Wt, bias, Cv, ldc, cofs, Kd,
                               blockIdx.x, blockIdx.y, lds);
}

// ---------- fused 5-segment GEMM (K=384, N=1920); seg 0 pre-scales Q; seg 2 writes V^T ----------
struct FSegs {
  const unsigned short* A[5];
  unsigned short* out[5];     // out[2] = vt base
  int ldc[5];
  int cofs[5];
};

__global__ __launch_bounds__(256) void fgemm_k(FSegs fs, const unsigned short* __restrict__ Wt) {
  __shared__ char lds[49152];
  int tid = threadIdx.x;
  int lane = tid & 63, w = tid >> 6, g = lane >> 4, c = lane & 15;
  int wr = w >> 1, wc = w & 1;
  int m0 = blockIdx.y*128, n0 = blockIdx.x*64;
  int seg = n0 / 384;
  const unsigned short* A = fs.A[seg];
  int lrow = lane >> 3;
  int cswz = ((lane & 7) ^ lrow)*8;

  f32x4 acc[4][2];
#pragma unroll
  for (int mt = 0; mt < 4; ++mt)
#pragma unroll
    for (int nt = 0; nt < 2; ++nt) acc[mt][nt] = 0.f;

  {
    char* As = lds; char* Bs = lds + 16384;
#pragma unroll
    for (int i = 0; i < 4; ++i) {
      int rb = i*32 + w*8;
      gl16(A + (size_t)(m0 + rb + lrow)*384 + cswz, As + rb*128);
    }
#pragma unroll
    for (int i = 0; i < 2; ++i) {
      int rb = i*32 + w*8;
      gl16(Wt + (size_t)(n0 + rb + lrow)*384 + cswz, Bs + rb*128);
    }
  }
  __syncthreads();

  for (int kt = 0; kt < 6; ++kt) {
    char* Asc = lds + (kt & 1)*24576;
    char* Bsc = Asc + 16384;
    if (kt + 1 < 6) {
      char* Asn = lds + ((kt + 1) & 1)*24576;
      char* Bsn = Asn + 16384;
      int k0 = (kt + 1)*64;
#pragma unroll
      for (int i = 0; i < 4; ++i) {
        int rb = i*32 + w*8;
        gl16(A + (size_t)(m0 + rb + lrow)*384 + k0 + cswz, Asn + rb*128);
      }
#pragma unroll
      for (int i = 0; i < 2; ++i) {
        int rb = i*32 + w*8;
        gl16(Wt + (size_t)(n0 + rb + lrow)*384 + k0 + cswz, Bsn + rb*128);
      }
    }
#pragma unroll
    for (int kb = 0; kb < 2; ++kb) {
      bf16x8 af[4], bfr[2];
#pragma unroll
      for (int mt = 0; mt < 4; ++mt) {
        int row = wr*64 + mt*16 + c;
        int ch = (kb*4 + g) ^ (row & 7);
        af[mt] = *(const bf16x8*)(Asc + row*128 + ch*16);
      }
#pragma unroll
      for (int nt = 0; nt < 2; ++nt) {
        int row = wc*32 + nt*16 + c;
        int ch = (kb*4 + g) ^ (row & 7);
        bfr[nt] = *(const bf16x8*)(Bsc + row*128 + ch*16);
      }
#pragma unroll
      for (int mt = 0; mt < 4; ++mt)
#pragma unroll
        for (int nt = 0; nt < 2; ++nt)
          acc[mt][nt] = __builtin_amdgcn_mfma_f32_16x16x32_bf16(af[mt], bfr[nt], acc[mt][nt], 0, 0, 0);
    }
    __syncthreads();
  }

  if (seg == 2) {
    unsigned short* vtp = fs.out[2];
    int bb = m0 >> 11;
    int tokb = (m0 & 2047) + wr*64 + 4*g;
#pragma unroll
    for (int mt = 0; mt < 4; ++mt) {
#pragma unroll
      for (int nt = 0; nt < 2; ++nt) {
        int cseg = (n0 - 768) + wc*32 + nt*16 + c;
        int h = cseg >> 6, d = cseg & 63;
        u32x2 pv;
        pv[0] = cvtpk(acc[mt][nt][0], acc[mt][nt][1]);
        pv[1] = cvtpk(acc[mt][nt][2], acc[mt][nt][3]);
        *(u32x2*)(vtp + ((size_t)((bb*NH + h)*64 + d))*NN + tokb + mt*16) = pv;
      }
    }
    return;
  }

  float qs = (seg == 0) ? 0.18033688011112042f : 1.0f;
  unsigned short* outp = fs.out[seg];
  int ldcs = fs.ldc[seg];
  int cbase = fs.cofs[seg] + (n0 - seg*384);
#pragma unroll
  for (int mt = 0; mt < 4; ++mt) {
#pragma unroll
    for (int nt = 0; nt < 2; ++nt) {
      int coln = cbase + wc*32 + nt*16 + c;
#pragma unroll
      for (int r = 0; r < 4; ++r) {
        int m = m0 + wr*64 + mt*16 + 4*g + r;
        outp[(size_t)m*ldcs + coln] = f2b(acc[mt][nt][r]*qs);
      }
    }
  }
}

// ---------- MFMA flash attention: software-pipelined (QK of kt+1 before softmax/PV of kt) ----------
// LDS 40KB: K0|V0|K1|V1 (8KB each) | PT 8KB. K staged 2 ahead, V 1 ahead; 1 barrier/tile.
__global__ __launch_bounds__(256) void flashm_k(const unsigned short* __restrict__ qkvb,
                                                const unsigned short* __restrict__ vt,
                                                unsigned short* __restrict__ o) {
  __shared__ char smem[40960];
  char* PT = smem + 32768;
  int bid = blockIdx.x;
  int s = (bid & 7)*96 + (bid >> 3);
  int qt = s & 31; int hb = s >> 5;
  int h = hb % NH, b = hb / NH;
  int q0 = qt*64;
  int tid = threadIdx.x;
  int w = tid >> 6, lane = tid & 63, g = lane >> 4, c = lane & 15;
  int lrow = lane >> 3;
  int gsw = ((lane & 7) ^ lrow)*8;

  const unsigned short* kbase = qkvb + (size_t)b*NN*1152 + 384 + h*64;
  const unsigned short* vbase = vt + ((size_t)(b*NH + h))*64*NN;

  bf16x8 qf[2];
  {
    const unsigned short* qrow = qkvb + ((size_t)(b*NN + q0 + w*16 + c))*1152 + h*64;
    qf[0] = *(const bf16x8*)(qrow + 8*g);
    qf[1] = *(const bf16x8*)(qrow + 32 + 8*g);
  }
  bf16x8 onesv;
#pragma unroll
  for (int i = 0; i < 8; ++i) onesv[i] = (short)0x3F80;

  f32x4 oacc[4];
#pragma unroll
  for (int i = 0; i < 4; ++i) oacc[i] = 0.f;
  f32x4 lacc = 0.f;

  // buffers: K slot s at smem + s*16384; V slot s at smem + s*16384 + 8192
#define KSTAGE(sl, ktb) { \
    char* KB = smem + (sl)*16384; \
    gl16(kbase + (size_t)((ktb)*64 + w*16 + lrow)*1152 + gsw,     KB + (w*16)*128); \
    gl16(kbase + (size_t)((ktb)*64 + w*16 + 8 + lrow)*1152 + gsw, KB + (w*16+8)*128); }
#define VSTAGE(sl, ktb) { \
    char* VB = smem + (sl)*16384 + 8192; \
    gl16(vbase + (size_t)(w*16 + lrow)*NN + (ktb)*64 + gsw,     VB + (w*16)*128); \
    gl16(vbase + (size_t)(w*16 + 8 + lrow)*NN + (ktb)*64 + gsw, VB + (w*16+8)*128); }

#define QKT(dst, sl) { \
    char* KB = smem + (sl)*16384; \
    _Pragma("unroll") \
    for (int nt = 0; nt < 4; ++nt) { \
      int krow = nt*16 + c; \
      _Pragma("unroll") \
      for (int kb = 0; kb < 2; ++kb) { \
        int ch = ((kb*4 + g) ^ (krow & 7))*16; \
        bf16x8 kf_ = *(const bf16x8*)(KB + krow*128 + ch); \
        dst[nt] = __builtin_amdgcn_mfma_f32_16x16x32_bf16(kf_, qf[kb], dst[nt], 0, 0, 0); \
      } \
    } }

  // prologue: K(0), K(1), V(0); first QK
  KSTAGE(0, 0);
  KSTAGE(1, 1);
  VSTAGE(0, 0);
  __syncthreads();

  f32x4 sTc[4], sTn[4];
#pragma unroll
  for (int nt = 0; nt < 4; ++nt) sTc[nt] = 0.f;
  __builtin_amdgcn_s_setprio(1);
  QKT(sTc, 0);
  __builtin_amdgcn_s_setprio(0);
  __syncthreads();   // protects K slot 0 from iteration-0 stage (tile 2)

  int prow = w*16 + c;
  int pswz = (c & 7) << 4;

  for (int kt = 0; kt < 32; ++kt) {
    // QK of tile kt+1 (K already resident in slot (kt+1)&1) — independent of softmax below
    if (kt + 1 < 32) {
#pragma unroll
      for (int nt = 0; nt < 4; ++nt) sTn[nt] = 0.f;
      __builtin_amdgcn_s_setprio(1);
      QKT(sTn, (kt + 1) & 1);
      __builtin_amdgcn_s_setprio(0);
    }

    // softmax of tile kt
#pragma unroll
    for (int nt = 0; nt < 4; ++nt) {
      float p0 = __builtin_amdgcn_exp2f(sTc[nt][0]);
      float p1 = __builtin_amdgcn_exp2f(sTc[nt][1]);
      float p2 = __builtin_amdgcn_exp2f(sTc[nt][2]);
      float p3 = __builtin_amdgcn_exp2f(sTc[nt][3]);
      u32x2 pk;
      pk[0] = cvtpk(p0, p1);
      pk[1] = cvtpk(p2, p3);
      *(u32x2*)(PT + prow*128 + ((nt*32 + 8*g) ^ pswz)) = pk;
    }

    bf16x8 pb[2];
#pragma unroll
    for (int kb = 0; kb < 2; ++kb)
      pb[kb] = *(const bf16x8*)(PT + prow*128 + (((kb*4 + g) ^ (c & 7))*16));

    // PV of tile kt
    __builtin_amdgcn_s_setprio(1);
    lacc = __builtin_amdgcn_mfma_f32_16x16x32_bf16(onesv, pb[0], lacc, 0, 0, 0);
    lacc = __builtin_amdgcn_mfma_f32_16x16x32_bf16(onesv, pb[1], lacc, 0, 0, 0);
    {
      char* VTc = smem + (kt & 1)*16384 + 8192;
#pragma unroll
      for (int dt = 0; dt < 4; ++dt) {
        int vrow = dt*16 + c;
#pragma unroll
        for (int kb = 0; kb < 2; ++kb) {
          int ch = ((kb*4 + g) ^ (vrow & 7))*16;
          bf16x8 vf = *(const bf16x8*)(VTc + vrow*128 + ch);
          oacc[dt] = __builtin_amdgcn_mfma_f32_16x16x32_bf16(vf, pb[kb], oacc[dt], 0, 0, 0);
        }
      }
    }
    __builtin_amdgcn_s_setprio(0);

    // stage K(kt+2) into K slot kt&1 (last read at iter kt-1, barrier-separated);
    // stage V(kt+1) into V slot (kt+1)&1 (last read at iter kt-1, barrier-separated)
    if (kt + 2 < 32) KSTAGE(kt & 1, kt + 2);
    if (kt + 1 < 32) VSTAGE((kt + 1) & 1, kt + 1);
    __syncthreads();   // drains staging; frees read buffers

#pragma unroll
    for (int nt = 0; nt < 4; ++nt) sTc[nt] = sTn[nt];
  }
#undef KSTAGE
#undef VSTAGE
#undef QKT

  float inv = 1.f / lacc[0];
  size_t orow = ((size_t)b*NN + q0 + w*16 + c)*DD + h*64;
#pragma unroll
  for (int dt = 0; dt < 4; ++dt) {
    u32x2 ov;
    ov[0] = cvtpk(oacc[dt][0]*inv, oacc[dt][1]*inv);
    ov[1] = cvtpk(oacc[dt][2]*inv, oacc[dt][3]*inv);
    *(u32x2*)(o + orow + dt*16 + 4*g) = ov;
  }
}

// ---------- KNN top-8: lane-min filter -> ballot compaction -> u64 sort-64 ----------
__global__ __launch_bounds__(256) void knn2_k(const float* __restrict__ qc4,
                                              const float* __restrict__ kc4,
                                              int* __restrict__ idx1,
                                              int* __restrict__ idx2) {
  __shared__ unsigned long long sbuf[4][64];
  const float* kcs = blockIdx.y ? kc4 : qc4;
  int* idxo = blockIdx.y ? idx2 : idx1;
  int lane = threadIdx.x & 63;
  int w = threadIdx.x >> 6;
  int q = blockIdx.x*4 + w;
  int b = q >> 11;
  f4 qv = *(const f4*)(qc4 + (size_t)q*4);
  float mx_ = -2.f*qv[0], my_ = -2.f*qv[1], mz_ = -2.f*qv[2];
  const float* kb = kcs + (size_t)b*NN*4;

  float fv[32];
  float fm = INFINITY;
#pragma unroll
  for (int i = 0; i < 32; ++i) {
    f4 kv = *(const f4*)(kb + (size_t)(lane + i*64)*4);
    float f = fmaf(mx_, kv[0], fmaf(my_, kv[1], fmaf(mz_, kv[2], kv[3])));
    fv[i] = f;
    fm = fminf(fm, f);
  }

  {
    float v = fm;
#pragma unroll
    for (int k = 2; k <= 64; k <<= 1) {
#pragma unroll
      for (int j = k >> 1; j >= 1; j >>= 1) {
        float p = __shfl_xor(v, j);
        bool tmin = (((lane & k) == 0) == ((lane & j) == 0));
        v = tmin ? fminf(v, p) : fmaxf(v, p);
      }
    }
    fm = __shfl(v, 7);
  }
  float T = fm;

  int cnt = 0;
#pragma unroll
  for (int i = 0; i < 32; ++i) {
    bool p = fv[i] <= T;
    unsigned long long mask = __ballot(p);
    if (mask) {
      if (p) {
        int off = cnt + (int)__popcll(mask & ((1ull << lane) - 1ull));
        unsigned u = __builtin_bit_cast(unsigned, fv[i]);
        u ^= 0x80000000u | (unsigned)((int)u >> 31);
        if (off < 64)
          sbuf[w][off] = ((unsigned long long)u << 32) | (unsigned)(lane + i*64);
      }
      cnt += (int)__popcll(mask);
    }
  }

  unsigned long long key = ~0ull;
  if (lane < cnt && lane < 64) key = sbuf[w][lane];
#pragma unroll
  for (int k = 2; k <= 64; k <<= 1) {
#pragma unroll
    for (int j = k >> 1; j >= 1; j >>= 1) {
      unsigned long long p = shfl_xor_u64(key, j);
      bool tmin = (((lane & k) == 0) == ((lane & j) == 0));
      bool less = key < p;
      unsigned long long mn = less ? key : p;
      unsigned long long mx = less ? p : key;
      key = tmin ? mn : mx;
    }
  }
  if (lane < 8) idxo[(size_t)q*8 + lane] = (int)(unsigned)key;
}

// ---------- geom body (256 threads, 1.5 cols each) ----------
__device__ __forceinline__ void geom_body(const unsigned short* __restrict__ GCb,
                                          const float* __restrict__ bias,
                                          const int* __restrict__ idx,
                                          unsigned short* __restrict__ out,
                                          int q) {
  int b = q >> 11;
  int t = threadIdx.x;
  int j[8];
#pragma unroll
  for (int k = 0; k < 8; ++k) j[k] = idx[(size_t)q*8 + k];
  const unsigned short* base = GCb + ((size_t)(b << 11))*768;
  {
    float c = b2f(GCb[(size_t)q*768 + 384 + t]) + bias[t];
    float mx = -INFINITY;
#pragma unroll
    for (int k = 0; k < 8; ++k) {
      float y = b2f(base[(size_t)j[k]*768 + t]) + c;
      y = (y > 0.f) ? y : 0.2f*y;
      mx = fmaxf(mx, y);
    }
    out[(size_t)q*768 + 384 + t] = f2b(mx);
  }
  if (t < 128) {
    int d = t + 256;
    float c = b2f(GCb[(size_t)q*768 + 384 + d]) + bias[d];
    float mx = -INFINITY;
#pragma unroll
    for (int k = 0; k < 8; ++k) {
      float y = b2f(base[(size_t)j[k]*768 + d]) + c;
      y = (y > 0.f) ? y : 0.2f*y;
      mx = fmaxf(mx, y);
    }
    out[(size_t)q*768 + 384 + d] = f2b(mx);
  }
}

// ---------- fused: 768 WO-gemm (halfM) blocks + 8192 geom blocks, 1:11 interleave ----------
__global__ __launch_bounds__(256) void wog_k(const unsigned short* __restrict__ A,
                                             const unsigned short* __restrict__ Wt,
                                             const float* __restrict__ wob,
                                             unsigned short* __restrict__ attnG,
                                             const unsigned short* __restrict__ GCb,
                                             const float* __restrict__ gbias,
                                             const int* __restrict__ idx) {
  __shared__ char lds[32768];
  int bid = blockIdx.x;
  int gq;
  if (bid < 8448) {
    int t = bid / 11, r = bid - t*11;
    if (r == 0) {
      mgemm_body<0,0,1,1>(A, 384, Wt, wob, attnG, 768, 0, 384, t % 6, t / 6, lds);
      return;
    }
    gq = t*10 + (r - 1);
  } else {
    gq = 7680 + (bid - 8448);
  }
  geom_body(GCb, gbias, idx, attnG, gq);
}

extern "C" void kernel_launch(void* const* d_in, const int* in_sizes, int n_in,
                              void* d_out, int out_size, void* d_ws, size_t ws_size,
                              hipStream_t stream) {
  (void)in_sizes; (void)n_in; (void)out_size; (void)ws_size;
  const float* qpts  = (const float*)d_in[0];
  const float* kpts  = (const float*)d_in[1];
  const float* ln_s  = (const float*)d_in[2];
  const float* ln_b  = (const float*)d_in[3];
  const float* qkvW  = (const float*)d_in[4];
  const float* Wo    = (const float*)d_in[5];
  const float* bo    = (const float*)d_in[6];
  const float* ffW1  = (const float*)d_in[7];
  const float* ffb1  = (const float*)d_in[8];
  const float* ffW2  = (const float*)d_in[9];
  const float* ffb2  = (const float*)d_in[10];
  const float* ffns  = (const float*)d_in[11];
  const float* ffnb  = (const float*)d_in[12];
  const float* knn1W = (const float*)d_in[13];
  const float* knn1b = (const float*)d_in[14];
  const float* knn2W = (const float*)d_in[15];
  const float* knn2b = (const float*)d_in[16];
  const float* smW   = (const float*)d_in[17];
  const float* smb   = (const float*)d_in[18];
  const float* cmW   = (const float*)d_in[19];
  const float* cmb   = (const float*)d_in[20];
  const float* cnqs  = (const float*)d_in[21];
  const float* cnqb  = (const float*)d_in[22];
  const float* cnks  = (const float*)d_in[23];
  const float* cnkb  = (const float*)d_in[24];
  const float* cqW   = (const float*)d_in[25];
  const float* ckW   = (const float*)d_in[26];
  const float* cvW   = (const float*)d_in[27];

  float* ws = (float*)d_ws;
  float* qc4  = ws;
  float* kc4  = qc4 + 32768;
  float* qf   = kc4 + 32768;
  float* kf   = qf + 3145728;
  unsigned short* nrmb = (unsigned short*)(kf + 3145728);
  unsigned short* nkb  = (unsigned short*)(kf + 3145728 + 1572864);
  float* qkv = kf + 3145728 + 1572864 + 1572864;
  unsigned short* qkvb   = (unsigned short*)qkv;
  unsigned short* attnGb = (unsigned short*)qkv;
  unsigned short* vtb    = (unsigned short*)(qkv + 4718592);
  unsigned short* wtb    = (unsigned short*)(qkv + 4718592 + 1572864);
  unsigned short* attnOb = (unsigned short*)(qkv + 4718592 + 1572864 + 1400832);
  unsigned short* GCbb   = (unsigned short*)((float*)attnOb + 1572864);
  int* idx1 = (int*)((float*)GCbb + 3145728);
  int* idx2 = idx1 + 65536;

  const int W_FA=0, W_WO=737280, W_SM=884736, W_FB=1179648,
            W_CM=1916928, W_FF1=2211840, W_FF2=2506752;

  WSrcs srcs;
  srcs.p[0]=qkvW; srcs.p[1]=knn1W; srcs.p[2]=knn1W; srcs.p[3]=Wo; srcs.p[4]=smW;
  srcs.p[5]=cqW; srcs.p[6]=ckW; srcs.p[7]=cvW; srcs.p[8]=knn2W; srcs.p[9]=knn2W;
  srcs.p[10]=cmW; srcs.p[11]=ffW1; srcs.p[12]=ffW2;
  wtrans_k<<<2736, 256, 0, stream>>>(srcs, wtb);

  dim3 tgrid(13, 64, NB), tblk(32, 8);
  split_k<<<tgrid, tblk, 0, stream>>>(qpts, qc4, qf);
  split_k<<<tgrid, tblk, 0, stream>>>(kpts, kc4, kf);

  knn2_k<<<dim3(2048, 2), 256, 0, stream>>>(qc4, kc4, idx1, idx2);

  dim3 mg384h(6, 128), mg768(12, 64), fg(30, 64);

  // ---- self attention branch ----
  ln_k<<<2048, 256, 0, stream>>>(qf, ln_s, ln_b, nrmb);
  {
    FSegs fa;
    for (int s = 0; s < 5; ++s) fa.A[s] = nrmb;
    fa.out[0] = qkvb; fa.ldc[0] = 1152; fa.cofs[0] = 0;
    fa.out[1] = qkvb; fa.ldc[1] = 1152; fa.cofs[1] = 384;
    fa.out[2] = vtb;  fa.ldc[2] = 0;    fa.cofs[2] = 0;
    fa.out[3] = GCbb; fa.ldc[3] = 768;  fa.cofs[3] = 0;
    fa.out[4] = GCbb; fa.ldc[4] = 768;  fa.cofs[4] = 384;
    fgemm_k<<<fg, 256, 0, stream>>>(fa, wtb + W_FA);
  }
  flashm_k<<<768, 256, 0, stream>>>(qkvb, vtb, attnOb);
  wog_k<<<8960, 256, 0, stream>>>(attnOb, wtb+W_WO, bo, attnGb, GCbb, knn1b, idx1);
  mgemm_k<0,1,0,1><<<mg384h, 256, 0, stream>>>(attnGb, 768, wtb+W_SM, smb, qf, DD, 0, 768);

  // ---- cross attention branch ----
  ln2_k<<<dim3(2048, 2), 256, 0, stream>>>(qf, cnqs, cnqb, nrmb, kf, cnks, cnkb, nkb);
  {
    FSegs fb;
    fb.A[0] = nrmb; fb.A[1] = nkb; fb.A[2] = nkb; fb.A[3] = nkb; fb.A[4] = nrmb;
    fb.out[0] = qkvb; fb.ldc[0] = 1152; fb.cofs[0] = 0;
    fb.out[1] = qkvb; fb.ldc[1] = 1152; fb.cofs[1] = 384;
    fb.out[2] = vtb;  fb.ldc[2] = 0;    fb.cofs[2] = 0;
    fb.out[3] = GCbb; fb.ldc[3] = 768;  fb.cofs[3] = 0;
    fb.out[4] = GCbb; fb.ldc[4] = 768;  fb.cofs[4] = 384;
    fgemm_k<<<fg, 256, 0, stream>>>(fb, wtb + W_FB);
  }
  flashm_k<<<768, 256, 0, stream>>>(qkvb, vtb, attnOb);
  wog_k<<<8960, 256, 0, stream>>>(attnOb, wtb+W_WO, bo, attnGb, GCbb, knn2b, idx2);
  mgemm_k<0,1,0,1><<<mg384h, 256, 0, stream>>>(attnGb, 768, wtb+W_CM, cmb, qf, DD, 0, 768);

  // ---- FFN ----
  ln_k<<<2048, 256, 0, stream>>>(qf, ffns, ffnb, nrmb);
  mgemm_k<1,0,1,0><<<mg768, 256, 0, stream>>>(nrmb, DD, wtb+W_FF1, ffb1, attnGb, 768, 0, DD);
  mgemm_k<0,1,0,1><<<mg384h, 256, 0, stream>>>(attnGb, 768, wtb+W_FF2, ffb2, qf, DD, 0, 768);

  pack_k<<<tgrid, tblk, 0, stream>>>(qc4, qf, (float*)d_out);
}

// Round 19
// 308.828 us; speedup vs baseline: 1.0103x; 1.0103x over previous
//
#include <hip/hip_runtime.h>
#include <cstdint>
#include <cstddef>

#define NB 4
#define NN 2048
#define DD 384
#define NH 6

typedef float f4 __attribute__((ext_vector_type(4)));
typedef float f32x4 __attribute__((ext_vector_type(4)));
typedef short bf16x8 __attribute__((ext_vector_type(8)));
typedef unsigned u32x2 __attribute__((ext_vector_type(2)));

__device__ __forceinline__ float gelu_t(float x) {
  float x3 = x*x*x;
  return 0.5f*x*(1.0f + tanhf(0.7978845608028654f*(x + 0.044715f*x3)));
}

__device__ __forceinline__ unsigned short f2b(float f) {
  unsigned u = __builtin_bit_cast(unsigned, f);
  u += 0x7fffu + ((u >> 16) & 1u);
  return (unsigned short)(u >> 16);
}

__device__ __forceinline__ float b2f(unsigned short u) {
  return __builtin_bit_cast(float, ((unsigned)u) << 16);
}

__device__ __forceinline__ unsigned cvtpk(float a, float b) {
  unsigned r;
  asm("v_cvt_pk_bf16_f32 %0, %1, %2" : "=v"(r) : "v"(a), "v"(b));
  return r;
}

typedef __attribute__((address_space(1))) const void gvoid_t;
typedef __attribute__((address_space(3))) void lvoid_t;
__device__ __forceinline__ void gl16(const void* g, void* l) {
  __builtin_amdgcn_global_load_lds((gvoid_t*)g, (lvoid_t*)l, 16, 0, 0);
}

__device__ __forceinline__ unsigned long long shfl_xor_u64(unsigned long long v, int m) {
  unsigned lo = (unsigned)v, hi = (unsigned)(v >> 32);
  lo = (unsigned)__shfl_xor((int)lo, m);
  hi = (unsigned)__shfl_xor((int)hi, m);
  return ((unsigned long long)hi << 32) | lo;
}

// ---------- split (B,387,N) -> coords xyzw (B,N,4) incl. w=|p|^2, feats (B,N,384) ----------
__global__ __launch_bounds__(256) void split_k(const float* __restrict__ pts,
                                               float* __restrict__ coords,
                                               float* __restrict__ feats) {
  __shared__ float t[32][33];
  int b = blockIdx.z;
  int c0 = blockIdx.x*32, n0 = blockIdx.y*32;
  int tx = threadIdx.x, ty = threadIdx.y;
#pragma unroll
  for (int i = 0; i < 4; ++i) {
    int c = c0 + ty + i*8;
    if (c < 387) t[ty+i*8][tx] = pts[((size_t)b*387 + c)*NN + n0 + tx];
  }
  __syncthreads();
#pragma unroll
  for (int i = 0; i < 4; ++i) {
    int n = n0 + ty + i*8;
    int c = c0 + tx;
    if (c < 387) {
      float v = t[tx][ty+i*8];
      if (c < 3) coords[((size_t)b*NN + n)*4 + c] = v;
      else       feats[((size_t)b*NN + n)*DD + (c-3)] = v;
    }
    if (c0 == 0 && tx == 3) {
      float x = t[0][ty+i*8], y = t[1][ty+i*8], z = t[2][ty+i*8];
      coords[((size_t)b*NN + n)*4 + 3] = x*x + y*y + z*z;
    }
  }
}

// ---------- pack coords+feats -> (B,387,N) ----------
__global__ __launch_bounds__(256) void pack_k(const float* __restrict__ coords,
                                              const float* __restrict__ feats,
                                              float* __restrict__ out) {
  __shared__ float t[32][33];
  int b = blockIdx.z;
  int c0 = blockIdx.x*32, n0 = blockIdx.y*32;
  int tx = threadIdx.x, ty = threadIdx.y;
#pragma unroll
  for (int i = 0; i < 4; ++i) {
    int n = n0 + ty + i*8;
    int c = c0 + tx;
    if (c < 387) {
      float v = (c < 3) ? coords[((size_t)b*NN + n)*4 + c]
                        : feats[((size_t)b*NN + n)*DD + (c-3)];
      t[tx][ty+i*8] = v;
    }
  }
  __syncthreads();
#pragma unroll
  for (int i = 0; i < 4; ++i) {
    int c = c0 + ty + i*8;
    if (c < 387) out[((size_t)b*387 + c)*NN + n0 + tx] = t[ty+i*8][tx];
  }
}

// ---------- LayerNorm ----------
__device__ __forceinline__ void ln_body(const float* __restrict__ x,
                                        const float* __restrict__ g,
                                        const float* __restrict__ bb,
                                        unsigned short* __restrict__ o,
                                        int row) {
  int lane = threadIdx.x & 63;
  const float* xr = x + (size_t)row*DD;
  float v[6]; float s = 0.f;
#pragma unroll
  for (int i = 0; i < 6; ++i) { v[i] = xr[lane + i*64]; s += v[i]; }
#pragma unroll
  for (int off = 1; off < 64; off <<= 1) s += __shfl_xor(s, off);
  float mean = s * (1.f/384.f);
  float s2 = 0.f;
#pragma unroll
  for (int i = 0; i < 6; ++i) { float d = v[i] - mean; s2 += d*d; }
#pragma unroll
  for (int off = 1; off < 64; off <<= 1) s2 += __shfl_xor(s2, off);
  float rs = rsqrtf(s2*(1.f/384.f) + 1e-5f);
  unsigned short* orow = o + (size_t)row*DD;
#pragma unroll
  for (int i = 0; i < 6; ++i) {
    int c = lane + i*64;
    orow[c] = f2b((v[i]-mean)*rs*g[c] + bb[c]);
  }
}

__global__ __launch_bounds__(256) void ln_k(const float* __restrict__ x,
                                            const float* __restrict__ g,
                                            const float* __restrict__ bb,
                                            unsigned short* __restrict__ o) {
  ln_body(x, g, bb, o, blockIdx.x*4 + (threadIdx.x >> 6));
}

__global__ __launch_bounds__(256) void ln2_k(const float* __restrict__ x1,
                                             const float* __restrict__ g1,
                                             const float* __restrict__ b1,
                                             unsigned short* __restrict__ o1,
                                             const float* __restrict__ x2,
                                             const float* __restrict__ g2,
                                             const float* __restrict__ b2,
                                             unsigned short* __restrict__ o2) {
  int row = blockIdx.x*4 + (threadIdx.x >> 6);
  if (blockIdx.y == 0) ln_body(x1, g1, b1, o1, row);
  else                 ln_body(x2, g2, b2, o2, row);
}

// ---------- one-shot weight transpose+convert ----------
struct WSrcs { const float* p[13]; };

__global__ __launch_bounds__(256) void wtrans_k(WSrcs srcs, unsigned short* __restrict__ dst) {
  constexpr int KK[13]  = {384,384,384,384,768,384,384,384,384,384,768,384,768};
  constexpr int NW[13]  = {1152,384,384,384,384,384,384,384,384,384,384,768,384};
  constexpr int MD[13]  = {0,0,2,0,0,0,0,0,0,2,0,0,0};
  constexpr int OFF[13] = {0,442368,589824,737280,884736,1179648,1327104,1474560,
                           1622016,1769472,1916928,2211840,2506752};
  constexpr int PFX[14] = {0,432,576,720,864,1152,1296,1440,1584,1728,1872,2160,2448,2736};
  int bid = blockIdx.x;
  int e = 0;
  while (bid >= PFX[e+1]) ++e;
  int t = bid - PFX[e];
  int K = KK[e], N = NW[e];
  int ntiles = N >> 5;
  int kt = t / ntiles, nt = t - kt*ntiles;
  const float* src = srcs.p[e];
  __shared__ float T[32][33];
  int tx = threadIdx.x & 31, ty = threadIdx.x >> 5;
  int n = nt*32 + tx;
#pragma unroll
  for (int i = 0; i < 4; ++i) {
    int k = kt*32 + ty + i*8;
    float v = src[(size_t)k*N + n];
    if (MD[e] == 2) v = src[(size_t)(k+384)*N + n] - v;
    T[ty+i*8][tx] = v;
  }
  __syncthreads();
#pragma unroll
  for (int i = 0; i < 4; ++i) {
    int nn = nt*32 + ty + i*8;
    int kk = kt*32 + tx;
    dst[(size_t)OFF[e] + (size_t)nn*K + kk] = f2b(T[tx][ty+i*8]);
  }
}

// ---------- MFMA bf16 GEMM body (dbuf gl16 staging) ----------
template<int ACT, int ACC, int OB, int HALFM>
__device__ __forceinline__ void mgemm_body(const unsigned short* __restrict__ A, int lda,
                                           const unsigned short* __restrict__ Wt,
                                           const float* __restrict__ bias,
                                           void* __restrict__ Cv, int ldc, int cofs,
                                           int Kd, int bx, int by, char* lds) {
  constexpr int BM   = HALFM ? 64 : 128;
  constexpr int MT   = HALFM ? 2 : 4;
  constexpr int AG   = HALFM ? 2 : 4;
  constexpr int ABUF = BM*128;
  constexpr int BUFSZ = ABUF + 8192;
  int tid = threadIdx.x;
  int lane = tid & 63, w = tid >> 6, g = lane >> 4, c = lane & 15;
  int wr = w >> 1, wc = w & 1;
  int m0 = by*BM, n0 = bx*64;
  int lrow = lane >> 3;
  int cswz = ((lane & 7) ^ lrow)*8;

  f32x4 acc[MT][2];
#pragma unroll
  for (int mt = 0; mt < MT; ++mt)
#pragma unroll
    for (int nt = 0; nt < 2; ++nt) acc[mt][nt] = 0.f;

  int KT = Kd >> 6;
  {
    char* As = lds; char* Bs = lds + ABUF;
#pragma unroll
    for (int i = 0; i < AG; ++i) {
      int rb = i*32 + w*8;
      gl16(A + (size_t)(m0 + rb + lrow)*lda + cswz, As + rb*128);
    }
#pragma unroll
    for (int i = 0; i < 2; ++i) {
      int rb = i*32 + w*8;
      gl16(Wt + (size_t)(n0 + rb + lrow)*Kd + cswz, Bs + rb*128);
    }
  }
  __syncthreads();

  for (int kt = 0; kt < KT; ++kt) {
    char* Asc = lds + (kt & 1)*BUFSZ;
    char* Bsc = Asc + ABUF;
    if (kt + 1 < KT) {
      char* Asn = lds + ((kt + 1) & 1)*BUFSZ;
      char* Bsn = Asn + ABUF;
      int k0 = (kt + 1)*64;
#pragma unroll
      for (int i = 0; i < AG; ++i) {
        int rb = i*32 + w*8;
        gl16(A + (size_t)(m0 + rb + lrow)*lda + k0 + cswz, Asn + rb*128);
      }
#pragma unroll
      for (int i = 0; i < 2; ++i) {
        int rb = i*32 + w*8;
        gl16(Wt + (size_t)(n0 + rb + lrow)*Kd + k0 + cswz, Bsn + rb*128);
      }
    }
#pragma unroll
    for (int kb = 0; kb < 2; ++kb) {
      bf16x8 af[MT], bfr[2];
#pragma unroll
      for (int mt = 0; mt < MT; ++mt) {
        int row = wr*(BM/2) + mt*16 + c;
        int ch = (kb*4 + g) ^ (row & 7);
        af[mt] = *(const bf16x8*)(Asc + row*128 + ch*16);
      }
#pragma unroll
      for (int nt = 0; nt < 2; ++nt) {
        int row = wc*32 + nt*16 + c;
        int ch = (kb*4 + g) ^ (row & 7);
        bfr[nt] = *(const bf16x8*)(Bsc + row*128 + ch*16);
      }
#pragma unroll
      for (int mt = 0; mt < MT; ++mt)
#pragma unroll
        for (int nt = 0; nt < 2; ++nt)
          acc[mt][nt] = __builtin_amdgcn_mfma_f32_16x16x32_bf16(af[mt], bfr[nt], acc[mt][nt], 0, 0, 0);
    }
    __syncthreads();
  }

#pragma unroll
  for (int mt = 0; mt < MT; ++mt) {
#pragma unroll
    for (int nt = 0; nt < 2; ++nt) {
      int coln = n0 + wc*32 + nt*16 + c;
      float bval = bias ? bias[coln] : 0.f;
#pragma unroll
      for (int r = 0; r < 4; ++r) {
        int m = m0 + wr*(BM/2) + mt*16 + 4*g + r;
        float t = acc[mt][nt][r] + bval;
        if (ACT == 1) t = gelu_t(t);
        if (OB) {
          ((unsigned short*)Cv)[(size_t)m*ldc + cofs + coln] = f2b(t);
        } else {
          float* cp = (float*)Cv + (size_t)m*ldc + cofs + coln;
          if (ACC) t += *cp;
          *cp = t;
        }
      }
    }
  }
}

template<int ACT, int ACC, int OB, int HALFM>
__global__ __launch_bounds__(256) void mgemm_k(const unsigned short* __restrict__ A, int lda,
                                               const unsigned short* __restrict__ Wt,
                                               const float* __restrict__ bias,
                                               void* __restrict__ Cv, int ldc, int cofs,
                                               int Kd) {
  constexpr int BM = HALFM ? 64 : 128;
  __shared__ char lds[2*(BM*128 + 8192)];
  mgemm_body<ACT,ACC,OB,HALFM>(A, lda, Wt, bias, Cv, ldc, cofs, Kd,
                               blockIdx.x, blockIdx.y, lds);
}

// ---------- fused 5-segment GEMM (K=384, N=1920); seg 0 pre-scales Q; seg 2 writes V^T ----------
struct FSegs {
  const unsigned short* A[5];
  unsigned short* out[5];     // out[2] = vt base
  int ldc[5];
  int cofs[5];
};

__global__ __launch_bounds__(256) void fgemm_k(FSegs fs, const unsigned short* __restrict__ Wt) {
  __shared__ char lds[49152];
  int tid = threadIdx.x;
  int lane = tid & 63, w = tid >> 6, g = lane >> 4, c = lane & 15;
  int wr = w >> 1, wc = w & 1;
  int m0 = blockIdx.y*128, n0 = blockIdx.x*64;
  int seg = n0 / 384;
  const unsigned short* A = fs.A[seg];
  int lrow = lane >> 3;
  int cswz = ((lane & 7) ^ lrow)*8;

  f32x4 acc[4][2];
#pragma unroll
  for (int mt = 0; mt < 4; ++mt)
#pragma unroll
    for (int nt = 0; nt < 2; ++nt) acc[mt][nt] = 0.f;

  {
    char* As = lds; char* Bs = lds + 16384;
#pragma unroll
    for (int i = 0; i < 4; ++i) {
      int rb = i*32 + w*8;
      gl16(A + (size_t)(m0 + rb + lrow)*384 + cswz, As + rb*128);
    }
#pragma unroll
    for (int i = 0; i < 2; ++i) {
      int rb = i*32 + w*8;
      gl16(Wt + (size_t)(n0 + rb + lrow)*384 + cswz, Bs + rb*128);
    }
  }
  __syncthreads();

  for (int kt = 0; kt < 6; ++kt) {
    char* Asc = lds + (kt & 1)*24576;
    char* Bsc = Asc + 16384;
    if (kt + 1 < 6) {
      char* Asn = lds + ((kt + 1) & 1)*24576;
      char* Bsn = Asn + 16384;
      int k0 = (kt + 1)*64;
#pragma unroll
      for (int i = 0; i < 4; ++i) {
        int rb = i*32 + w*8;
        gl16(A + (size_t)(m0 + rb + lrow)*384 + k0 + cswz, Asn + rb*128);
      }
#pragma unroll
      for (int i = 0; i < 2; ++i) {
        int rb = i*32 + w*8;
        gl16(Wt + (size_t)(n0 + rb + lrow)*384 + k0 + cswz, Bsn + rb*128);
      }
    }
#pragma unroll
    for (int kb = 0; kb < 2; ++kb) {
      bf16x8 af[4], bfr[2];
#pragma unroll
      for (int mt = 0; mt < 4; ++mt) {
        int row = wr*64 + mt*16 + c;
        int ch = (kb*4 + g) ^ (row & 7);
        af[mt] = *(const bf16x8*)(Asc + row*128 + ch*16);
      }
#pragma unroll
      for (int nt = 0; nt < 2; ++nt) {
        int row = wc*32 + nt*16 + c;
        int ch = (kb*4 + g) ^ (row & 7);
        bfr[nt] = *(const bf16x8*)(Bsc + row*128 + ch*16);
      }
#pragma unroll
      for (int mt = 0; mt < 4; ++mt)
#pragma unroll
        for (int nt = 0; nt < 2; ++nt)
          acc[mt][nt] = __builtin_amdgcn_mfma_f32_16x16x32_bf16(af[mt], bfr[nt], acc[mt][nt], 0, 0, 0);
    }
    __syncthreads();
  }

  if (seg == 2) {
    unsigned short* vtp = fs.out[2];
    int bb = m0 >> 11;
    int tokb = (m0 & 2047) + wr*64 + 4*g;
#pragma unroll
    for (int mt = 0; mt < 4; ++mt) {
#pragma unroll
      for (int nt = 0; nt < 2; ++nt) {
        int cseg = (n0 - 768) + wc*32 + nt*16 + c;
        int h = cseg >> 6, d = cseg & 63;
        u32x2 pv;
        pv[0] = cvtpk(acc[mt][nt][0], acc[mt][nt][1]);
        pv[1] = cvtpk(acc[mt][nt][2], acc[mt][nt][3]);
        *(u32x2*)(vtp + ((size_t)((bb*NH + h)*64 + d))*NN + tokb + mt*16) = pv;
      }
    }
    return;
  }

  // seg 0 (Q): fold softmax scale 0.125*log2(e) into Q so flash uses exp2(s) directly
  float qs = (seg == 0) ? 0.18033688011112042f : 1.0f;
  unsigned short* outp = fs.out[seg];
  int ldcs = fs.ldc[seg];
  int cbase = fs.cofs[seg] + (n0 - seg*384);
#pragma unroll
  for (int mt = 0; mt < 4; ++mt) {
#pragma unroll
    for (int nt = 0; nt < 2; ++nt) {
      int coln = cbase + wc*32 + nt*16 + c;
#pragma unroll
      for (int r = 0; r < 4; ++r) {
        int m = m0 + wr*64 + mt*16 + 4*g + r;
        outp[(size_t)m*ldcs + coln] = f2b(acc[mt][nt][r]*qs);
      }
    }
  }
}

// ---------- MFMA flash attention: gl16 dbuf, pre-scaled Q, ones-MFMA lsum, setprio ----------
__global__ __launch_bounds__(256) void flashm_k(const unsigned short* __restrict__ qkvb,
                                                const unsigned short* __restrict__ vt,
                                                unsigned short* __restrict__ o) {
  __shared__ char smem[40960];
  char* PT = smem + 32768;
  int bid = blockIdx.x;
  int s = (bid & 7)*96 + (bid >> 3);
  int qt = s & 31; int hb = s >> 5;
  int h = hb % NH, b = hb / NH;
  int q0 = qt*64;
  int tid = threadIdx.x;
  int w = tid >> 6, lane = tid & 63, g = lane >> 4, c = lane & 15;
  int lrow = lane >> 3;
  int gsw = ((lane & 7) ^ lrow)*8;

  const unsigned short* kbase = qkvb + (size_t)b*NN*1152 + 384 + h*64;
  const unsigned short* vbase = vt + ((size_t)(b*NH + h))*64*NN;

  bf16x8 qf[2];
  {
    const unsigned short* qrow = qkvb + ((size_t)(b*NN + q0 + w*16 + c))*1152 + h*64;
    qf[0] = *(const bf16x8*)(qrow + 8*g);
    qf[1] = *(const bf16x8*)(qrow + 32 + 8*g);
  }
  bf16x8 onesv;
#pragma unroll
  for (int i = 0; i < 8; ++i) onesv[i] = (short)0x3F80;

  f32x4 oacc[4];
#pragma unroll
  for (int i = 0; i < 4; ++i) oacc[i] = 0.f;
  f32x4 lacc = 0.f;

#define FSTAGE(bf, ktb) { \
    char* KB = smem + (bf)*16384; char* VB = KB + 8192; \
    gl16(kbase + (size_t)((ktb) + w*16 + lrow)*1152 + gsw,     KB + (w*16)*128); \
    gl16(kbase + (size_t)((ktb) + w*16 + 8 + lrow)*1152 + gsw, KB + (w*16+8)*128); \
    gl16(vbase + (size_t)(w*16 + lrow)*NN + (ktb) + gsw,       VB + (w*16)*128); \
    gl16(vbase + (size_t)(w*16 + 8 + lrow)*NN + (ktb) + gsw,   VB + (w*16+8)*128); }

  FSTAGE(0, 0);
  __syncthreads();

  for (int kt = 0; kt < 32; ++kt) {
    if (kt + 1 < 32) FSTAGE((kt + 1) & 1, (kt + 1)*64);
    char* KTc = smem + (kt & 1)*16384;
    char* VTc = KTc + 8192;

    f32x4 sT[4];
#pragma unroll
    for (int nt = 0; nt < 4; ++nt) sT[nt] = 0.f;
    __builtin_amdgcn_s_setprio(1);
#pragma unroll
    for (int nt = 0; nt < 4; ++nt) {
      int krow = nt*16 + c;
#pragma unroll
      for (int kb = 0; kb < 2; ++kb) {
        int ch = ((kb*4 + g) ^ (krow & 7))*16;
        bf16x8 kf_ = *(const bf16x8*)(KTc + krow*128 + ch);
        sT[nt] = __builtin_amdgcn_mfma_f32_16x16x32_bf16(kf_, qf[kb], sT[nt], 0, 0, 0);
      }
    }
    __builtin_amdgcn_s_setprio(0);

    int prow = w*16 + c;
    int pswz = (c & 7) << 4;
#pragma unroll
    for (int nt = 0; nt < 4; ++nt) {
      float p0 = __builtin_amdgcn_exp2f(sT[nt][0]);
      float p1 = __builtin_amdgcn_exp2f(sT[nt][1]);
      float p2 = __builtin_amdgcn_exp2f(sT[nt][2]);
      float p3 = __builtin_amdgcn_exp2f(sT[nt][3]);
      u32x2 pk;
      pk[0] = cvtpk(p0, p1);
      pk[1] = cvtpk(p2, p3);
      *(u32x2*)(PT + prow*128 + ((nt*32 + 8*g) ^ pswz)) = pk;
    }

    bf16x8 pb[2];
#pragma unroll
    for (int kb = 0; kb < 2; ++kb)
      pb[kb] = *(const bf16x8*)(PT + prow*128 + (((kb*4 + g) ^ (c & 7))*16));

    __builtin_amdgcn_s_setprio(1);
    lacc = __builtin_amdgcn_mfma_f32_16x16x32_bf16(onesv, pb[0], lacc, 0, 0, 0);
    lacc = __builtin_amdgcn_mfma_f32_16x16x32_bf16(onesv, pb[1], lacc, 0, 0, 0);

#pragma unroll
    for (int dt = 0; dt < 4; ++dt) {
      int vrow = dt*16 + c;
#pragma unroll
      for (int kb = 0; kb < 2; ++kb) {
        int ch = ((kb*4 + g) ^ (vrow & 7))*16;
        bf16x8 vf = *(const bf16x8*)(VTc + vrow*128 + ch);
        oacc[dt] = __builtin_amdgcn_mfma_f32_16x16x32_bf16(vf, pb[kb], oacc[dt], 0, 0, 0);
      }
    }
    __builtin_amdgcn_s_setprio(0);
    __syncthreads();
  }
#undef FSTAGE

  float inv = 1.f / lacc[0];
  size_t orow = ((size_t)b*NN + q0 + w*16 + c)*DD + h*64;
#pragma unroll
  for (int dt = 0; dt < 4; ++dt) {
    u32x2 ov;
    ov[0] = cvtpk(oacc[dt][0]*inv, oacc[dt][1]*inv);
    ov[1] = cvtpk(oacc[dt][2]*inv, oacc[dt][3]*inv);
    *(u32x2*)(o + orow + dt*16 + 4*g) = ov;
  }
}

// ---------- KNN top-8: lane-min filter -> ballot compaction -> u64 sort-64 ----------
__global__ __launch_bounds__(256) void knn2_k(const float* __restrict__ qc4,
                                              const float* __restrict__ kc4,
                                              int* __restrict__ idx1,
                                              int* __restrict__ idx2) {
  __shared__ unsigned long long sbuf[4][64];
  const float* kcs = blockIdx.y ? kc4 : qc4;
  int* idxo = blockIdx.y ? idx2 : idx1;
  int lane = threadIdx.x & 63;
  int w = threadIdx.x >> 6;
  int q = blockIdx.x*4 + w;
  int b = q >> 11;
  f4 qv = *(const f4*)(qc4 + (size_t)q*4);
  float mx_ = -2.f*qv[0], my_ = -2.f*qv[1], mz_ = -2.f*qv[2];
  const float* kb = kcs + (size_t)b*NN*4;

  float fv[32];
  float fm = INFINITY;
#pragma unroll
  for (int i = 0; i < 32; ++i) {
    f4 kv = *(const f4*)(kb + (size_t)(lane + i*64)*4);
    float f = fmaf(mx_, kv[0], fmaf(my_, kv[1], fmaf(mz_, kv[2], kv[3])));
    fv[i] = f;
    fm = fminf(fm, f);
  }

  {
    float v = fm;
#pragma unroll
    for (int k = 2; k <= 64; k <<= 1) {
#pragma unroll
      for (int j = k >> 1; j >= 1; j >>= 1) {
        float p = __shfl_xor(v, j);
        bool tmin = (((lane & k) == 0) == ((lane & j) == 0));
        v = tmin ? fminf(v, p) : fmaxf(v, p);
      }
    }
    fm = __shfl(v, 7);
  }
  float T = fm;

  int cnt = 0;
#pragma unroll
  for (int i = 0; i < 32; ++i) {
    bool p = fv[i] <= T;
    unsigned long long mask = __ballot(p);
    if (mask) {
      if (p) {
        int off = cnt + (int)__popcll(mask & ((1ull << lane) - 1ull));
        unsigned u = __builtin_bit_cast(unsigned, fv[i]);
        u ^= 0x80000000u | (unsigned)((int)u >> 31);
        if (off < 64)
          sbuf[w][off] = ((unsigned long long)u << 32) | (unsigned)(lane + i*64);
      }
      cnt += (int)__popcll(mask);
    }
  }

  unsigned long long key = ~0ull;
  if (lane < cnt && lane < 64) key = sbuf[w][lane];
#pragma unroll
  for (int k = 2; k <= 64; k <<= 1) {
#pragma unroll
    for (int j = k >> 1; j >= 1; j >>= 1) {
      unsigned long long p = shfl_xor_u64(key, j);
      bool tmin = (((lane & k) == 0) == ((lane & j) == 0));
      bool less = key < p;
      unsigned long long mn = less ? key : p;
      unsigned long long mx = less ? p : key;
      key = tmin ? mn : mx;
    }
  }
  if (lane < 8) idxo[(size_t)q*8 + lane] = (int)(unsigned)key;
}

// ---------- geom body (256 threads, 1.5 cols each) ----------
__device__ __forceinline__ void geom_body(const unsigned short* __restrict__ GCb,
                                          const float* __restrict__ bias,
                                          const int* __restrict__ idx,
                                          unsigned short* __restrict__ out,
                                          int q) {
  int b = q >> 11;
  int t = threadIdx.x;
  int j[8];
#pragma unroll
  for (int k = 0; k < 8; ++k) j[k] = idx[(size_t)q*8 + k];
  const unsigned short* base = GCb + ((size_t)(b << 11))*768;
  {
    float c = b2f(GCb[(size_t)q*768 + 384 + t]) + bias[t];
    float mx = -INFINITY;
#pragma unroll
    for (int k = 0; k < 8; ++k) {
      float y = b2f(base[(size_t)j[k]*768 + t]) + c;
      y = (y > 0.f) ? y : 0.2f*y;
      mx = fmaxf(mx, y);
    }
    out[(size_t)q*768 + 384 + t] = f2b(mx);
  }
  if (t < 128) {
    int d = t + 256;
    float c = b2f(GCb[(size_t)q*768 + 384 + d]) + bias[d];
    float mx = -INFINITY;
#pragma unroll
    for (int k = 0; k < 8; ++k) {
      float y = b2f(base[(size_t)j[k]*768 + d]) + c;
      y = (y > 0.f) ? y : 0.2f*y;
      mx = fmaxf(mx, y);
    }
    out[(size_t)q*768 + 384 + d] = f2b(mx);
  }
}

// ---------- fused: 768 WO-gemm (halfM) blocks + 8192 geom blocks, 1:11 interleave ----------
__global__ __launch_bounds__(256) void wog_k(const unsigned short* __restrict__ A,
                                             const unsigned short* __restrict__ Wt,
                                             const float* __restrict__ wob,
                                             unsigned short* __restrict__ attnG,
                                             const unsigned short* __restrict__ GCb,
                                             const float* __restrict__ gbias,
                                             const int* __restrict__ idx) {
  __shared__ char lds[32768];
  int bid = blockIdx.x;
  int gq;
  if (bid < 8448) {
    int t = bid / 11, r = bid - t*11;
    if (r == 0) {
      mgemm_body<0,0,1,1>(A, 384, Wt, wob, attnG, 768, 0, 384, t % 6, t / 6, lds);
      return;
    }
    gq = t*10 + (r - 1);
  } else {
    gq = 7680 + (bid - 8448);
  }
  geom_body(GCb, gbias, idx, attnG, gq);
}

extern "C" void kernel_launch(void* const* d_in, const int* in_sizes, int n_in,
                              void* d_out, int out_size, void* d_ws, size_t ws_size,
                              hipStream_t stream) {
  (void)in_sizes; (void)n_in; (void)out_size; (void)ws_size;
  const float* qpts  = (const float*)d_in[0];
  const float* kpts  = (const float*)d_in[1];
  const float* ln_s  = (const float*)d_in[2];
  const float* ln_b  = (const float*)d_in[3];
  const float* qkvW  = (const float*)d_in[4];
  const float* Wo    = (const float*)d_in[5];
  const float* bo    = (const float*)d_in[6];
  const float* ffW1  = (const float*)d_in[7];
  const float* ffb1  = (const float*)d_in[8];
  const float* ffW2  = (const float*)d_in[9];
  const float* ffb2  = (const float*)d_in[10];
  const float* ffns  = (const float*)d_in[11];
  const float* ffnb  = (const float*)d_in[12];
  const float* knn1W = (const float*)d_in[13];
  const float* knn1b = (const float*)d_in[14];
  const float* knn2W = (const float*)d_in[15];
  const float* knn2b = (const float*)d_in[16];
  const float* smW   = (const float*)d_in[17];
  const float* smb   = (const float*)d_in[18];
  const float* cmW   = (const float*)d_in[19];
  const float* cmb   = (const float*)d_in[20];
  const float* cnqs  = (const float*)d_in[21];
  const float* cnqb  = (const float*)d_in[22];
  const float* cnks  = (const float*)d_in[23];
  const float* cnkb  = (const float*)d_in[24];
  const float* cqW   = (const float*)d_in[25];
  const float* ckW   = (const float*)d_in[26];
  const float* cvW   = (const float*)d_in[27];

  float* ws = (float*)d_ws;
  float* qc4  = ws;
  float* kc4  = qc4 + 32768;
  float* qf   = kc4 + 32768;
  float* kf   = qf + 3145728;
  unsigned short* nrmb = (unsigned short*)(kf + 3145728);
  unsigned short* nkb  = (unsigned short*)(kf + 3145728 + 1572864);
  float* qkv = kf + 3145728 + 1572864 + 1572864;
  unsigned short* qkvb   = (unsigned short*)qkv;
  unsigned short* attnGb = (unsigned short*)qkv;
  unsigned short* vtb    = (unsigned short*)(qkv + 4718592);
  unsigned short* wtb    = (unsigned short*)(qkv + 4718592 + 1572864);
  unsigned short* attnOb = (unsigned short*)(qkv + 4718592 + 1572864 + 1400832);
  unsigned short* GCbb   = (unsigned short*)((float*)attnOb + 1572864);
  int* idx1 = (int*)((float*)GCbb + 3145728);
  int* idx2 = idx1 + 65536;

  const int W_FA=0, W_WO=737280, W_SM=884736, W_FB=1179648,
            W_CM=1916928, W_FF1=2211840, W_FF2=2506752;

  WSrcs srcs;
  srcs.p[0]=qkvW; srcs.p[1]=knn1W; srcs.p[2]=knn1W; srcs.p[3]=Wo; srcs.p[4]=smW;
  srcs.p[5]=cqW; srcs.p[6]=ckW; srcs.p[7]=cvW; srcs.p[8]=knn2W; srcs.p[9]=knn2W;
  srcs.p[10]=cmW; srcs.p[11]=ffW1; srcs.p[12]=ffW2;
  wtrans_k<<<2736, 256, 0, stream>>>(srcs, wtb);

  dim3 tgrid(13, 64, NB), tblk(32, 8);
  split_k<<<tgrid, tblk, 0, stream>>>(qpts, qc4, qf);
  split_k<<<tgrid, tblk, 0, stream>>>(kpts, kc4, kf);

  knn2_k<<<dim3(2048, 2), 256, 0, stream>>>(qc4, kc4, idx1, idx2);

  dim3 mg384h(6, 128), mg768(12, 64), fg(30, 64);

  // ---- self attention branch ----
  ln_k<<<2048, 256, 0, stream>>>(qf, ln_s, ln_b, nrmb);
  {
    FSegs fa;
    for (int s = 0; s < 5; ++s) fa.A[s] = nrmb;
    fa.out[0] = qkvb; fa.ldc[0] = 1152; fa.cofs[0] = 0;
    fa.out[1] = qkvb; fa.ldc[1] = 1152; fa.cofs[1] = 384;
    fa.out[2] = vtb;  fa.ldc[2] = 0;    fa.cofs[2] = 0;
    fa.out[3] = GCbb; fa.ldc[3] = 768;  fa.cofs[3] = 0;
    fa.out[4] = GCbb; fa.ldc[4] = 768;  fa.cofs[4] = 384;
    fgemm_k<<<fg, 256, 0, stream>>>(fa, wtb + W_FA);
  }
  flashm_k<<<768, 256, 0, stream>>>(qkvb, vtb, attnOb);
  wog_k<<<8960, 256, 0, stream>>>(attnOb, wtb+W_WO, bo, attnGb, GCbb, knn1b, idx1);
  mgemm_k<0,1,0,1><<<mg384h, 256, 0, stream>>>(attnGb, 768, wtb+W_SM, smb, qf, DD, 0, 768);

  // ---- cross attention branch ----
  ln2_k<<<dim3(2048, 2), 256, 0, stream>>>(qf, cnqs, cnqb, nrmb, kf, cnks, cnkb, nkb);
  {
    FSegs fb;
    fb.A[0] = nrmb; fb.A[1] = nkb; fb.A[2] = nkb; fb.A[3] = nkb; fb.A[4] = nrmb;
    fb.out[0] = qkvb; fb.ldc[0] = 1152; fb.cofs[0] = 0;
    fb.out[1] = qkvb; fb.ldc[1] = 1152; fb.cofs[1] = 384;
    fb.out[2] = vtb;  fb.ldc[2] = 0;    fb.cofs[2] = 0;
    fb.out[3] = GCbb; fb.ldc[3] = 768;  fb.cofs[3] = 0;
    fb.out[4] = GCbb; fb.ldc[4] = 768;  fb.cofs[4] = 384;
    fgemm_k<<<fg, 256, 0, stream>>>(fb, wtb + W_FB);
  }
  flashm_k<<<768, 256, 0, stream>>>(qkvb, vtb, attnOb);
  wog_k<<<8960, 256, 0, stream>>>(attnOb, wtb+W_WO, bo, attnGb, GCbb, knn2b, idx2);
  mgemm_k<0,1,0,1><<<mg384h, 256, 0, stream>>>(attnGb, 768, wtb+W_CM, cmb, qf, DD, 0, 768);

  // ---- FFN ----
  ln_k<<<2048, 256, 0, stream>>>(qf, ffns, ffnb, nrmb);
  mgemm_k<1,0,1,0><<<mg768, 256, 0, stream>>>(nrmb, DD, wtb+W_FF1, ffb1, attnGb, 768, 0, DD);
  mgemm_k<0,1,0,1><<<mg384h, 256, 0, stream>>>(attnGb, 768, wtb+W_FF2, ffb2, qf, DD, 0, 768);

  pack_k<<<tgrid, tblk, 0, stream>>>(qc4, qf, (float*)d_out);
}